// Round 1
// baseline (248.134 us; speedup 1.0000x reference)
//
#include <hip/hip_runtime.h>
#include <math.h>

// CapLayerLP: 20-iter predictor-corrector PDIP for
//   min 0.5*eps*||x||^2 + p.x  s.t. G x <= h
// with G = [1^T; -I; I; f^T; -f^T]  (n=1024, m=2n+3=2051).
// K = eps*I + diag(WL+WU) + WA*11^T + (WF+WFm)*ff^T  -> diagonal + rank-2,
// solved exactly via Woodbury (2x2 capacitance). All state in registers of
// a single 128-thread block; reductions via wave shfl + 2-slot LDS.

#define NT 128
#define NWAVE 2
#define K 8            // elements per thread; n = NT*K = 1024
#define NFEAT 1024

constexpr double EPSR  = 1e-4;
constexpr double CCAP  = 10.0;
constexpr int    ITERS = 20;
constexpr double MCON  = 2.0 * NFEAT + 3.0;   // m = 2051

__device__ __forceinline__ double wave_red_sum(double v) {
#pragma unroll
    for (int off = 32; off; off >>= 1) v += __shfl_down(v, off, 64);
    return v;  // valid in lane 0
}
__device__ __forceinline__ double wave_red_min(double v) {
#pragma unroll
    for (int off = 32; off; off >>= 1) v = fmin(v, __shfl_down(v, off, 64));
    return v;
}

// Multi-value block sum; result broadcast (identical bits) to all threads.
template <int NV>
__device__ __forceinline__ void block_sum_n(double* v, double* lds) {
    const int wid = threadIdx.x >> 6, lane = threadIdx.x & 63;
#pragma unroll
    for (int j = 0; j < NV; ++j) v[j] = wave_red_sum(v[j]);
    __syncthreads();                 // protect lds from previous readers
    if (lane == 0) {
#pragma unroll
        for (int j = 0; j < NV; ++j) lds[j * NWAVE + wid] = v[j];
    }
    __syncthreads();
#pragma unroll
    for (int j = 0; j < NV; ++j) {
        double s = lds[j * NWAVE + 0];
#pragma unroll
        for (int w = 1; w < NWAVE; ++w) s += lds[j * NWAVE + w];
        v[j] = s;
    }
}

__device__ __forceinline__ double block_min1(double v, double* lds) {
    const int wid = threadIdx.x >> 6, lane = threadIdx.x & 63;
    v = wave_red_min(v);
    __syncthreads();
    if (lane == 0) lds[wid] = v;
    __syncthreads();
    double r = lds[0];
#pragma unroll
    for (int w = 1; w < NWAVE; ++w) r = fmin(r, lds[w]);
    return r;
}

__device__ __forceinline__ double rat(double v, double dv) {
    return dv < 0.0 ? (-v / dv) : (double)INFINITY;
}

__global__ void __launch_bounds__(NT, 1)
pdip_kernel(const float* __restrict__ xin, const int* __restrict__ male,
            float* __restrict__ out) {
    __shared__ double lds[5 * NWAVE];
    const int tid = threadIdx.x;

    double x[K], sL[K], zL[K], sU[K], zU[K], p[K], f[K];
#pragma unroll
    for (int k = 0; k < K; ++k) {
        const int i = tid + k * NT;
        p[k] = -(double)xin[i];
        f[k] = (double)male[i];
        x[k] = 0.0; sL[k] = 1.0; zL[k] = 1.0; sU[k] = 1.0; zU[k] = 1.0;
    }
    double sA = 1.0, zA = 1.0, sF = 1.0, zF = 1.0, sFm = 1.0, zFm = 1.0;

    double n_male;
    {
        double nm[1] = {0.0};
#pragma unroll
        for (int k = 0; k < K; ++k) nm[0] += f[k];
        block_sum_n<1>(nm, lds);
        n_male = nm[0];
    }
    const double hF  = CCAP * n_male / (double)NFEAT + 1.0;
    const double hFm = -(CCAP * n_male / (double)NFEAT);

    for (int it = 0; it < ITERS; ++it) {
        double invD[K], invSL[K], invSU[K], rx[K];
        double r5[5] = {0, 0, 0, 0, 0};  // Suu, Suv, sum(x), sum(f*x), s.z (vec part)
#pragma unroll
        for (int k = 0; k < K; ++k) {
            invSL[k] = 1.0 / sL[k];
            invSU[k] = 1.0 / sU[k];
            const double WL = zL[k] * invSL[k], WU = zU[k] * invSU[k];
            invD[k] = 1.0 / (EPSR + WL + WU);
            r5[0] += invD[k];
            r5[1] += f[k] * invD[k];
            r5[2] += x[k];
            r5[3] += f[k] * x[k];
            r5[4] += sL[k] * zL[k] + sU[k] * zU[k];
        }
        block_sum_n<5>(r5, lds);
        const double Suu = r5[0], Suv = r5[1], sx = r5[2], sfx = r5[3];
        const double mu = (r5[4] + sA * zA + sF * zF + sFm * zFm) / MCON;
        const double aw = zA / sA, bw = zF / sF + zFm / sFm;
        const double rpA  = sx + sA - CCAP;
        const double rpF  = sfx + sF - hF;
        const double rpFm = -sfx + sFm - hFm;
        const double M00 = 1.0 / aw + Suu, M01 = Suv, M11 = 1.0 / bw + Suv;
        const double detM = M00 * M11 - M01 * M01;
#pragma unroll
        for (int k = 0; k < K; ++k)
            rx[k] = EPSR * x[k] + p[k] + zA - zL[k] + zU[k] + f[k] * (zF - zFm);

        double dxv[K], dsLv[K], dsUv[K], dzLv[K], dzUv[K];
        double dsA, dzA, dsF, dzF, dsFm, dzFm;

        auto direction = [&](const double* rszL, const double* rszU,
                             double rszA, double rszF, double rszFm) {
            const double tA  = (zA * rpA - rszA) / sA;
            const double tF  = (zF * rpF - rszF) / sF;
            const double tFm = (zFm * rpFm - rszFm) / sFm;
            double y[K];
            double r2[2] = {0, 0};
#pragma unroll
            for (int k = 0; k < K; ++k) {
                const double rpL = sL[k] - x[k];
                const double rpU = x[k] + sU[k] - 1.0;
                const double tL = (zL[k] * rpL - rszL[k]) * invSL[k];
                const double tU = (zU[k] * rpU - rszU[k]) * invSU[k];
                const double rhs = -(rx[k] + tA - tL + tU + f[k] * (tF - tFm));
                y[k] = rhs * invD[k];
                r2[0] += y[k];
                r2[1] += f[k] * y[k];
            }
            block_sum_n<2>(r2, lds);
            const double alpha = (M11 * r2[0] - M01 * r2[1]) / detM;
            const double beta  = (M00 * r2[1] - M01 * r2[0]) / detM;
            double r2b[2] = {0, 0};
#pragma unroll
            for (int k = 0; k < K; ++k) {
                dxv[k] = y[k] - (alpha + beta * f[k]) * invD[k];
                r2b[0] += dxv[k];
                r2b[1] += f[k] * dxv[k];
            }
            block_sum_n<2>(r2b, lds);
            dsA  = -rpA - r2b[0];
            dsF  = -rpF - r2b[1];
            dsFm = -rpFm + r2b[1];
            dzA  = -(rszA + zA * dsA) / sA;
            dzF  = -(rszF + zF * dsF) / sF;
            dzFm = -(rszFm + zFm * dsFm) / sFm;
#pragma unroll
            for (int k = 0; k < K; ++k) {
                const double rpL = sL[k] - x[k];
                const double rpU = x[k] + sU[k] - 1.0;
                dsLv[k] = -rpL + dxv[k];
                dsUv[k] = -rpU - dxv[k];
                dzLv[k] = -(rszL[k] + zL[k] * dsLv[k]) * invSL[k];
                dzUv[k] = -(rszU[k] + zU[k] * dsUv[k]) * invSU[k];
            }
        };

        // ---------- predictor (affine) ----------
        double rszL[K], rszU[K];
#pragma unroll
        for (int k = 0; k < K; ++k) { rszL[k] = sL[k] * zL[k]; rszU[k] = sU[k] * zU[k]; }
        direction(rszL, rszU, sA * zA, sF * zF, sFm * zFm);

        double lmin = INFINITY;
#pragma unroll
        for (int k = 0; k < K; ++k) {
            lmin = fmin(lmin, rat(sL[k], dsLv[k]));
            lmin = fmin(lmin, rat(sU[k], dsUv[k]));
            lmin = fmin(lmin, rat(zL[k], dzLv[k]));
            lmin = fmin(lmin, rat(zU[k], dzUv[k]));
        }
        lmin = fmin(lmin, rat(sA, dsA));   lmin = fmin(lmin, rat(zA, dzA));
        lmin = fmin(lmin, rat(sF, dsF));   lmin = fmin(lmin, rat(zF, dzF));
        lmin = fmin(lmin, rat(sFm, dsFm)); lmin = fmin(lmin, rat(zFm, dzFm));
        const double a_aff = fmin(1.0, block_min1(lmin, lds));

        double macc[1] = {0.0};
#pragma unroll
        for (int k = 0; k < K; ++k) {
            macc[0] += (sL[k] + a_aff * dsLv[k]) * (zL[k] + a_aff * dzLv[k])
                     + (sU[k] + a_aff * dsUv[k]) * (zU[k] + a_aff * dzUv[k]);
        }
        block_sum_n<1>(macc, lds);
        const double mu_aff = (macc[0]
                             + (sA + a_aff * dsA) * (zA + a_aff * dzA)
                             + (sF + a_aff * dsF) * (zF + a_aff * dzF)
                             + (sFm + a_aff * dsFm) * (zFm + a_aff * dzFm)) / MCON;
        const double tmr = mu_aff / mu;
        const double sm = tmr * tmr * tmr * mu;  // sigma*mu

        // ---------- corrector ----------
#pragma unroll
        for (int k = 0; k < K; ++k) {
            rszL[k] = sL[k] * zL[k] + dsLv[k] * dzLv[k] - sm;
            rszU[k] = sU[k] * zU[k] + dsUv[k] * dzUv[k] - sm;
        }
        const double rszA  = sA * zA + dsA * dzA - sm;
        const double rszF  = sF * zF + dsF * dzF - sm;
        const double rszFmv = sFm * zFm + dsFm * dzFm - sm;
        direction(rszL, rszU, rszA, rszF, rszFmv);

        lmin = INFINITY;
#pragma unroll
        for (int k = 0; k < K; ++k) {
            lmin = fmin(lmin, rat(sL[k], dsLv[k]));
            lmin = fmin(lmin, rat(sU[k], dsUv[k]));
            lmin = fmin(lmin, rat(zL[k], dzLv[k]));
            lmin = fmin(lmin, rat(zU[k], dzUv[k]));
        }
        lmin = fmin(lmin, rat(sA, dsA));   lmin = fmin(lmin, rat(zA, dzA));
        lmin = fmin(lmin, rat(sF, dsF));   lmin = fmin(lmin, rat(zF, dzF));
        lmin = fmin(lmin, rat(sFm, dsFm)); lmin = fmin(lmin, rat(zFm, dzFm));
        const double astep = 0.99 * fmin(1.0, block_min1(lmin, lds));

#pragma unroll
        for (int k = 0; k < K; ++k) {
            x[k]  += astep * dxv[k];
            sL[k] += astep * dsLv[k]; zL[k] += astep * dzLv[k];
            sU[k] += astep * dsUv[k]; zU[k] += astep * dzUv[k];
        }
        sA += astep * dsA;   zA += astep * dzA;
        sF += astep * dsF;   zF += astep * dzF;
        sFm += astep * dsFm; zFm += astep * dzFm;
    }

#pragma unroll
    for (int k = 0; k < K; ++k) out[tid + k * NT] = (float)x[k];
}

extern "C" void kernel_launch(void* const* d_in, const int* in_sizes, int n_in,
                              void* d_out, int out_size, void* d_ws, size_t ws_size,
                              hipStream_t stream) {
    const float* xin = (const float*)d_in[0];
    const int* male  = (const int*)d_in[1];
    float* out = (float*)d_out;
    (void)in_sizes; (void)n_in; (void)out_size; (void)d_ws; (void)ws_size;
    pdip_kernel<<<1, NT, 0, stream>>>(xin, male, out);
}

// Round 2
// 98.398 us; speedup vs baseline: 2.5217x; 2.5217x over previous
//
#include <hip/hip_runtime.h>
#include <math.h>

// CapLayerLP: 20-iter Mehrotra PDIP, K = diag + rank-2 solved via Woodbury.
// n=1024, m=2051. 256 threads (4 waves, 1/SIMD), 4 elements/thread.
// 4 reduction rounds/iter: DPP butterfly (xor1,2,7,15) + single LDS exchange.

#define NT 256
#define KE 4

constexpr double EPSR  = 1e-4;
constexpr double CCAP  = 10.0;
constexpr int    ITERS = 20;
constexpr double NFEATD = 1024.0;
constexpr double INV_M  = 1.0 / (2.0 * 1024.0 + 3.0);

// DPP ctrl codes: quad_perm[1,0,3,2]=xor1, quad_perm[2,3,0,1]=xor2,
// row_half_mirror=xor7, row_mirror=xor15. XOR-mask span {1,2,7,15} = 4 bits.
#define XOR1  0xB1
#define XOR2  0x4E
#define XOR7  0x141
#define XOR15 0x140

template <int C> __device__ __forceinline__ double dppd(double v) {
    typedef int v2i __attribute__((ext_vector_type(2)));
    v2i a = __builtin_bit_cast(v2i, v);
    a.x = __builtin_amdgcn_update_dpp(0, a.x, C, 0xF, 0xF, true);
    a.y = __builtin_amdgcn_update_dpp(0, a.y, C, 0xF, 0xF, true);
    return __builtin_bit_cast(double, a);
}
template <int C> __device__ __forceinline__ float dppf(float v) {
    int a = __builtin_bit_cast(int, v);
    a = __builtin_amdgcn_update_dpp(0, a, C, 0xF, 0xF, true);
    return __builtin_bit_cast(float, a);
}
__device__ __forceinline__ double rowsum_d(double v) {
    v += dppd<XOR1>(v); v += dppd<XOR2>(v); v += dppd<XOR7>(v); v += dppd<XOR15>(v);
    return v;
}
__device__ __forceinline__ float rowsum_f(float v) {
    v += dppf<XOR1>(v); v += dppf<XOR2>(v); v += dppf<XOR7>(v); v += dppf<XOR15>(v);
    return v;
}
__device__ __forceinline__ float rowmax_f(float v) {
    v = fmaxf(v, dppf<XOR1>(v)); v = fmaxf(v, dppf<XOR2>(v));
    v = fmaxf(v, dppf<XOR7>(v)); v = fmaxf(v, dppf<XOR15>(v));
    return v;
}

__global__ void __launch_bounds__(NT, 1)
pdip_kernel(const float* __restrict__ xin, const int* __restrict__ male,
            float* __restrict__ out) {
    __shared__ double LD1[5][16];   // R1: Suu, Suv, SZv, sy, sfy
    __shared__ double LD4[2][16];   // R4: syc, sfyc
    __shared__ double LDN[16];      // init: n_male
    __shared__ float  LF2[3][16];   // R2: rmax, S1, S2
    __shared__ float  LF5[16];      // R5: rmax corrector

    const int tid = threadIdx.x;
    const int w16 = tid >> 4;      // which 16-lane row in the block (0..15)
    const int sl  = tid & 15;

    double p[KE], f[KE], x[KE], sL[KE], zL[KE], sU[KE], zU[KE];
    {
        const float4 xv = reinterpret_cast<const float4*>(xin)[tid];
        const int4   mv = reinterpret_cast<const int4*>(male)[tid];
        p[0] = -(double)xv.x; p[1] = -(double)xv.y;
        p[2] = -(double)xv.z; p[3] = -(double)xv.w;
        f[0] = (double)mv.x; f[1] = (double)mv.y;
        f[2] = (double)mv.z; f[3] = (double)mv.w;
    }
#pragma unroll
    for (int k = 0; k < KE; ++k) { x[k] = 0.0; sL[k] = 1.0; zL[k] = 1.0; sU[k] = 1.0; zU[k] = 1.0; }
    double sA = 1.0, zA = 1.0, sF = 1.0, zF = 1.0, sFm = 1.0, zFm = 1.0;
    double sx = 0.0, sfx = 0.0;     // tracked sum(x), sum(f*x)

    // ---- n_male (one f64 round) ----
    double nm = f[0] + f[1] + f[2] + f[3];
    nm = rowsum_d(nm);
    if (sl == 0) LDN[w16] = nm;
    __syncthreads();
    nm = rowsum_d(LDN[sl]);
    const double hFv  = CCAP * nm / NFEATD + 1.0;
    const double hFmv = -(CCAP * nm / NFEATD);

    for (int it = 0; it < ITERS; ++it) {
        // ---- scalar inverses (1 divide for 6) ----
        const double c1 = sA, cs2 = c1 * zA, cs3 = cs2 * sF, cs4 = cs3 * zF,
                     cs5 = cs4 * sFm, cs6 = cs5 * zFm;
        double g = 1.0 / cs6;
        const double invZFm = g * cs5; g *= zFm;
        const double invSFm = g * cs4; g *= sFm;
        const double invZF  = g * cs3; g *= zF;
        const double invSF  = g * cs2; g *= sF;
        const double invZA  = g * c1;  g *= zA;
        const double invSA  = g;

        // predictor scalar t's (use tracked sx, sfx)
        const double tA  = zA  * (sx - CCAP)  * invSA;
        const double tF  = zF  * (sfx - hFv)  * invSF;
        const double tFm = zFm * (-sfx - hFmv) * invSFm;
        const double tFd = tF - tFm;
        const double zdF = zF - zFm;

        // ---- per-element inverses (1 divide for 5) + R1 accumulators + predictor y ----
        double isL[KE], isU[KE], izL[KE], izU[KE], iD[KE], rx[KE], y[KE];
        double r0 = 0.0, r1 = 0.0, r2 = 0.0, r3 = 0.0, r4 = 0.0;
#pragma unroll
        for (int k = 0; k < KE; ++k) {
            const double c2v = sL[k] * sU[k];
            const double numv = fma(EPSR, c2v, fma(zL[k], sU[k], zU[k] * sL[k]));
            const double c3v = c2v * zL[k], c4v = c3v * zU[k], c5v = c4v * numv;
            const double inv = 1.0 / c5v;
            const double invNum = inv * c4v;
            double gg = inv * numv;            // 1/c4
            izU[k] = gg * c3v; gg *= zU[k];    // 1/c3
            izL[k] = gg * c2v; gg *= zL[k];    // 1/c2
            isU[k] = gg * sL[k];
            isL[k] = gg * sU[k];
            iD[k]  = c2v * invNum;             // 1/(eps + zL/sL + zU/sU)

            rx[k] = fma(EPSR, x[k], p[k]) + (zA - zL[k] + zU[k]) + f[k] * zdF;
            // predictor: tL = -zL*x/sL, tU = zU*(x-1)/sU
            const double rhs = -(rx[k] + tA + zL[k] * x[k] * isL[k]
                                 + zU[k] * (x[k] - 1.0) * isU[k] + f[k] * tFd);
            y[k] = rhs * iD[k];
            r0 += iD[k];
            r1 += f[k] * iD[k];
            r2 += fma(sL[k], zL[k], sU[k] * zU[k]);
            r3 += y[k];
            r4 += f[k] * y[k];
        }
        // ---- R1 exchange (5 f64) ----
        r0 = rowsum_d(r0); r1 = rowsum_d(r1); r2 = rowsum_d(r2);
        r3 = rowsum_d(r3); r4 = rowsum_d(r4);
        if (sl == 0) { LD1[0][w16] = r0; LD1[1][w16] = r1; LD1[2][w16] = r2;
                       LD1[3][w16] = r3; LD1[4][w16] = r4; }
        __syncthreads();
        const double Suu = rowsum_d(LD1[0][sl]);
        const double Suv = rowsum_d(LD1[1][sl]);
        const double SZv = rowsum_d(LD1[2][sl]);
        const double sy  = rowsum_d(LD1[3][sl]);
        const double sfy = rowsum_d(LD1[4][sl]);

        const double SZ = SZv + sA * zA + sF * zF + sFm * zFm;
        const double mu = SZ * INV_M;
        const double rpA  = sx + sA - CCAP;
        const double rpF  = sfx + sF - hFv;
        const double rpFm = -sfx + sFm - hFmv;
        const double bw = zF * invSF + zFm * invSFm;
        const double M00 = sA * invZA + Suu;   // 1/aw + Suu
        const double M01 = Suv;
        const double M11 = 1.0 / bw + Suv;
        const double invdet = 1.0 / (M00 * M11 - M01 * M01);

        // predictor direction
        const double al = (M11 * sy - M01 * sfy) * invdet;
        const double be = (M00 * sfy - M01 * sy) * invdet;
        const double sdx  = sy - al * Suu - be * Suv;
        const double sfdx = sfy - (al + be) * Suv;
        const double dsA  = -rpA - sdx;
        const double dsF  = -rpF - sfdx;
        const double dsFm = -rpFm + sfdx;
        const double dzA  = -zA  * ((sA + dsA) * invSA);
        const double dzF  = -zF  * ((sF + dsF) * invSF);
        const double dzFm = -zFm * ((sFm + dsFm) * invSFm);

        double dsl[KE], dzl[KE], dsu[KE], dzu[KE];
        double rm = 0.0, S1 = 0.0, S2 = 0.0;
#pragma unroll
        for (int k = 0; k < KE; ++k) {
            const double dx = fma(-(al + be * f[k]), iD[k], y[k]);
            dsl[k] = (x[k] - sL[k]) + dx;
            dsu[k] = (1.0 - x[k] - sU[k]) - dx;
            dzl[k] = -zL[k] * ((sL[k] + dsl[k]) * isL[k]);
            dzu[k] = -zU[k] * ((sU[k] + dsu[k]) * isU[k]);
            rm = fmax(rm, fmax(fmax(-dsl[k] * isL[k], -dsu[k] * isU[k]),
                               fmax(-dzl[k] * izL[k], -dzu[k] * izU[k])));
            S1 += fma(sL[k], dzl[k], zL[k] * dsl[k]) + fma(sU[k], dzu[k], zU[k] * dsu[k]);
            S2 += fma(dsl[k], dzl[k], dsu[k] * dzu[k]);
        }
        rm = fmax(rm, fmax(fmax(-dsA * invSA, -dzA * invZA),
                  fmax(fmax(-dsF * invSF, -dzF * invZF),
                       fmax(-dsFm * invSFm, -dzFm * invZFm))));
        const double S1s = sA * dzA + zA * dsA + sF * dzF + zF * dsF + sFm * dzFm + zFm * dsFm;
        const double S2s = dsA * dzA + dsF * dzF + dsFm * dzFm;

        // ---- R2 exchange (f32: max, sum, sum) ----
        float rmf = rowmax_f((float)rm);
        float s1f = rowsum_f((float)S1);
        float s2f = rowsum_f((float)S2);
        if (sl == 0) { LF2[0][w16] = rmf; LF2[1][w16] = s1f; LF2[2][w16] = s2f; }
        __syncthreads();
        rmf = rowmax_f(LF2[0][sl]);
        s1f = rowsum_f(LF2[1][sl]);
        s2f = rowsum_f(LF2[2][sl]);

        const double a_aff = 1.0 / fmax((double)rmf, 1.0);
        const double S1t = (double)s1f + S1s, S2t = (double)s2f + S2s;
        const double mu_aff = fma(a_aff, fma(a_aff, S2t, S1t), SZ) * INV_M;
        const double sm = (mu_aff * mu_aff * mu_aff) / (mu * mu);   // sigma*mu

        // corrector scalar parts
        const double rszA  = fma(dsA, dzA, sA * zA) - sm;
        const double rszF  = fma(dsF, dzF, sF * zF) - sm;
        const double rszFm = fma(dsFm, dzFm, sFm * zFm) - sm;
        const double tAc  = (zA * rpA - rszA) * invSA;
        const double tFc  = (zF * rpF - rszF) * invSF;
        const double tFmc = (zFm * rpFm - rszFm) * invSFm;
        const double tFdc = tFc - tFmc;

        double rszl[KE], rszu[KE], yc[KE];
        double q0 = 0.0, q1 = 0.0;
#pragma unroll
        for (int k = 0; k < KE; ++k) {
            rszl[k] = fma(dsl[k], dzl[k], sL[k] * zL[k]) - sm;
            rszu[k] = fma(dsu[k], dzu[k], sU[k] * zU[k]) - sm;
            const double rpL = sL[k] - x[k];
            const double rpU = x[k] + sU[k] - 1.0;
            const double tLc = (zL[k] * rpL - rszl[k]) * isL[k];
            const double tUc = (zU[k] * rpU - rszu[k]) * isU[k];
            yc[k] = -(rx[k] + tAc - tLc + tUc + f[k] * tFdc) * iD[k];
            q0 += yc[k];
            q1 += f[k] * yc[k];
        }
        // ---- R4 exchange (2 f64) ----
        q0 = rowsum_d(q0); q1 = rowsum_d(q1);
        if (sl == 0) { LD4[0][w16] = q0; LD4[1][w16] = q1; }
        __syncthreads();
        const double syc  = rowsum_d(LD4[0][sl]);
        const double sfyc = rowsum_d(LD4[1][sl]);

        const double alc = (M11 * syc - M01 * sfyc) * invdet;
        const double bec = (M00 * sfyc - M01 * syc) * invdet;
        const double sdxc  = syc - alc * Suu - bec * Suv;
        const double sfdxc = sfyc - (alc + bec) * Suv;
        const double dsAc  = -rpA - sdxc;
        const double dsFc  = -rpF - sfdxc;
        const double dsFmc = -rpFm + sfdxc;
        const double dzAc  = -(rszA + zA * dsAc) * invSA;
        const double dzFc  = -(rszF + zF * dsFc) * invSF;
        const double dzFmc = -(rszFm + zFm * dsFmc) * invSFm;

        double dxc[KE];
        double rm2 = 0.0;
#pragma unroll
        for (int k = 0; k < KE; ++k) {
            dxc[k] = fma(-(alc + bec * f[k]), iD[k], yc[k]);
            dsl[k] = (x[k] - sL[k]) + dxc[k];
            dsu[k] = (1.0 - x[k] - sU[k]) - dxc[k];
            dzl[k] = -(rszl[k] + zL[k] * dsl[k]) * isL[k];
            dzu[k] = -(rszu[k] + zU[k] * dsu[k]) * isU[k];
            rm2 = fmax(rm2, fmax(fmax(-dsl[k] * isL[k], -dsu[k] * isU[k]),
                                 fmax(-dzl[k] * izL[k], -dzu[k] * izU[k])));
        }
        rm2 = fmax(rm2, fmax(fmax(-dsAc * invSA, -dzAc * invZA),
                   fmax(fmax(-dsFc * invSF, -dzFc * invZF),
                        fmax(-dsFmc * invSFm, -dzFmc * invZFm))));

        // ---- R5 exchange (1 f32 max) ----
        float rf2 = rowmax_f((float)rm2);
        if (sl == 0) LF5[w16] = rf2;
        __syncthreads();
        rf2 = rowmax_f(LF5[sl]);

        const double a = 0.99 / fmax((double)rf2, 1.0);

#pragma unroll
        for (int k = 0; k < KE; ++k) {
            x[k]  = fma(a, dxc[k], x[k]);
            sL[k] = fma(a, dsl[k], sL[k]);
            zL[k] = fma(a, dzl[k], zL[k]);
            sU[k] = fma(a, dsu[k], sU[k]);
            zU[k] = fma(a, dzu[k], zU[k]);
        }
        sA  = fma(a, dsAc, sA);   zA  = fma(a, dzAc, zA);
        sF  = fma(a, dsFc, sF);   zF  = fma(a, dzFc, zF);
        sFm = fma(a, dsFmc, sFm); zFm = fma(a, dzFmc, zFm);
        sx  = fma(a, sdxc, sx);
        sfx = fma(a, sfdxc, sfx);
    }

    float4 o;
    o.x = (float)x[0]; o.y = (float)x[1]; o.z = (float)x[2]; o.w = (float)x[3];
    reinterpret_cast<float4*>(out)[tid] = o;
}

extern "C" void kernel_launch(void* const* d_in, const int* in_sizes, int n_in,
                              void* d_out, int out_size, void* d_ws, size_t ws_size,
                              hipStream_t stream) {
    const float* xin = (const float*)d_in[0];
    const int* male  = (const int*)d_in[1];
    float* out = (float*)d_out;
    (void)in_sizes; (void)n_in; (void)out_size; (void)d_ws; (void)ws_size;
    pdip_kernel<<<1, NT, 0, stream>>>(xin, male, out);
}